// Round 8
// baseline (287.144 us; speedup 1.0000x reference)
//
#include <hip/hip_runtime.h>
#include <math.h>

#define BATCH 2
#define SEQ   2048
#define EMB   1024
#define NHEAD 16
#define DHEAD 64
#define MROWS (BATCH*SEQ)
#define QKVS  3072          // fused QKV row stride

typedef unsigned int  uint;
typedef unsigned short ushort;
typedef __attribute__((ext_vector_type(8))) short short8;
typedef __attribute__((ext_vector_type(4))) float f32x4;

// fast 2^x (bare v_exp_f32; avoids glibc __exp2f macro collision)
__device__ __forceinline__ float exp2_fast(float x) {
    return __builtin_amdgcn_exp2f(x);
}

// ---------------- positional encoding table ----------------
__global__ void pos_init(float* __restrict__ pos) {
    int s = blockIdx.x;
    int d = threadIdx.x;              // 0..63
    int i = d >> 1;
    float expo  = (float)(2 * i) / (float)DHEAD;
    float scale = 1.0f / (powf(10000.0f, expo) + 1.1920928955078125e-07f);
    float ang   = (float)s * scale;
    pos[s * DHEAD + d] = (d & 1) ? cosf(ang) : sinf(ang);
}

// ---------------- bf16 helpers ----------------
__device__ __forceinline__ uint pack_bf16x2(float a, float b) {
    union { float f; uint u; } x, y;
    x.f = a; y.f = b;
    uint ua = x.u + 0x7fffu + ((x.u >> 16) & 1u);   // RNE
    uint ub = y.u + 0x7fffu + ((y.u >> 16) & 1u);
    return (ua >> 16) | (ub & 0xffff0000u);
}
__device__ __forceinline__ ushort bf16_1(float a) {
    union { float f; uint u; } x; x.f = a;
    return (ushort)((x.u + 0x7fffu + ((x.u >> 16) & 1u)) >> 16);
}

// async global->LDS, 16B per lane (lds dest = wave-uniform base + lane*16)
__device__ __forceinline__ void gll16(const ushort* g, ushort* l) {
    __builtin_amdgcn_global_load_lds(
        (const __attribute__((address_space(1))) uint*)g,
        (__attribute__((address_space(3))) uint*)l, 16, 0, 0);
}

// ---------------- fp32 -> bf16 (rowmajor) ----------------
__global__ __launch_bounds__(256) void cvt_bf16(
    const float* __restrict__ in, ushort* __restrict__ out, int n2) {
    int gid = blockIdx.x * 256 + threadIdx.x;
    if (gid < n2) {
        float2 v = ((const float2*)in)[gid];
        ((uint*)out)[gid] = pack_bf16x2(v.x, v.y);
    }
}

// ------- all 4 weights: W[K][N] fp32 -> Wt[N][K] bf16 (transpose) ----------
__global__ __launch_bounds__(256) void wt_bf16_all(
    const float* __restrict__ Wq, const float* __restrict__ Wk,
    const float* __restrict__ Wv, const float* __restrict__ Wo,
    ushort* __restrict__ Wqkvt, ushort* __restrict__ Wot) {
    __shared__ float tile[32][33];
    const int which = blockIdx.z;
    const float* W = (which == 0) ? Wq : (which == 1) ? Wk : (which == 2) ? Wv : Wo;
    ushort* Wt = (which < 3) ? (Wqkvt + (size_t)which * 1024 * EMB) : Wot;
    const int c0 = blockIdx.x * 32;   // n-tile
    const int r0 = blockIdx.y * 32;   // k-tile
    const int tx = threadIdx.x & 31;
    const int ty = threadIdx.x >> 5;  // 0..7
#pragma unroll
    for (int i = 0; i < 4; ++i)
        tile[ty + i * 8][tx] = W[(size_t)(r0 + ty + i * 8) * EMB + c0 + tx];
    __syncthreads();
#pragma unroll
    for (int i = 0; i < 4; ++i)
        Wt[(size_t)(c0 + ty + i * 8) * EMB + r0 + tx] = bf16_1(tile[tx][ty + i * 8]);
}

// ---- QKV bf16 [token][3072] (V at col 2048) -> Vt bf16 [bh][64][SEQ] ------
__global__ __launch_bounds__(256) void vt_tr(
    const ushort* __restrict__ QKV, ushort* __restrict__ Vt) {
    __shared__ ushort tile[64][72];
    const int s0 = blockIdx.x * 64;
    const int bh = blockIdx.y;
    const int b  = bh >> 4, h = bh & 15;
    const int t  = threadIdx.x;
    const int r  = t >> 2;             // 0..63
    const int c  = (t & 3) * 16;       // 0,16,32,48
    const ushort* src = QKV + (size_t)(b * SEQ + s0 + r) * QKVS + 2048 + h * 64 + c;
    *(uint4*)&tile[r][c]     = *(const uint4*)src;
    *(uint4*)&tile[r][c + 8] = *(const uint4*)(src + 8);
    __syncthreads();
    uint ov[8];
#pragma unroll
    for (int i = 0; i < 8; ++i) {
        uint lo = tile[c + 2 * i][r];
        uint hi = tile[c + 2 * i + 1][r];
        ov[i] = lo | (hi << 16);
    }
    ushort* dst = Vt + ((size_t)bh * 64 + r) * SEQ + s0 + c;
    *(uint4*)dst       = *(uint4*)&ov[0];
    *(uint4*)(dst + 8) = *(uint4*)&ov[4];
}

// ------- bf16 MFMA GEMM (m97 recipe): C[M,N] = A[M,K] @ Bt[N,K]^T ----------
// posmode: cols<2048 get +pos; cols<1024 (Q) also folded *scale*log2e.
#define TM 128
#define TN 128
#define TK 32
#define SCLQ (0.03125f * 1.44269504088896f)

__global__ __launch_bounds__(256) void gemm_mfma2(
    const ushort* __restrict__ A, const ushort* __restrict__ Bt,
    void* __restrict__ Cv, const float* __restrict__ pos, int posmode,
    int out_bf16, int N, int K) {
    __shared__ ushort As[TM * TK];   // [m][k] contiguous (lane-linear for gll)
    __shared__ ushort Bs[TN * TK];   // [n][k]

    const int t    = threadIdx.x;
    const int lane = t & 63, w = t >> 6;
    const int quad = lane >> 4, l15 = lane & 15;
    const int bm = blockIdx.x * TM, bn = blockIdx.y * TN;
    const int wm = (w & 1) * 64, wn = (w >> 1) * 64;
    const int r0 = t >> 2, kp = (t & 3) * 8;   // staging row / k-part

    f32x4 acc[4][4];
#pragma unroll
    for (int mi = 0; mi < 4; ++mi)
#pragma unroll
        for (int ni = 0; ni < 4; ++ni)
            acc[mi][ni] = (f32x4){0.f, 0.f, 0.f, 0.f};

    const ushort* Ap0 = A  + (size_t)(bm + r0) * K + kp;
    const ushort* Ap1 = A  + (size_t)(bm + 64 + r0) * K + kp;
    const ushort* Bp0 = Bt + (size_t)(bn + r0) * K + kp;
    const ushort* Bp1 = Bt + (size_t)(bn + 64 + r0) * K + kp;
    ushort* Asd0 = &As[t * 8];
    ushort* Asd1 = &As[2048 + t * 8];
    ushort* Bsd0 = &Bs[t * 8];
    ushort* Bsd1 = &Bs[2048 + t * 8];

    for (int k0 = 0; k0 < K; k0 += TK) {
        __syncthreads();
        gll16(Ap0 + k0, Asd0);
        gll16(Ap1 + k0, Asd1);
        gll16(Bp0 + k0, Bsd0);
        gll16(Bp1 + k0, Bsd1);
        __syncthreads();

        short8 af[4], bfv[4];
#pragma unroll
        for (int mi = 0; mi < 4; ++mi)
            af[mi] = *(const short8*)&As[(wm + mi * 16 + l15) * TK + quad * 8];
#pragma unroll
        for (int ni = 0; ni < 4; ++ni)
            bfv[ni] = *(const short8*)&Bs[(wn + ni * 16 + l15) * TK + quad * 8];
#pragma unroll
        for (int mi = 0; mi < 4; ++mi)
#pragma unroll
            for (int ni = 0; ni < 4; ++ni)
                acc[mi][ni] = __builtin_amdgcn_mfma_f32_16x16x32_bf16(
                    af[mi], bfv[ni], acc[mi][ni], 0, 0, 0);
    }

#pragma unroll
    for (int mi = 0; mi < 4; ++mi) {
#pragma unroll
        for (int r = 0; r < 4; ++r) {
            const int row = bm + wm + mi * 16 + quad * 4 + r;
            const int s   = row & (SEQ - 1);
#pragma unroll
            for (int ni = 0; ni < 4; ++ni) {
                const int col = bn + wn + ni * 16 + l15;
                float v = acc[mi][ni][r];
                if (posmode) {
                    if (col < 2048) v += pos[s * DHEAD + (col & 63)];
                    if (col < 1024) v *= SCLQ;   // fold attn scale into Q
                }
                if (out_bf16) ((ushort*)Cv)[(size_t)row * N + col] = bf16_1(v);
                else          ((float*) Cv)[(size_t)row * N + col] = v;
            }
        }
    }
}

// ------ barrier-free MFMA flash attention (S^T form, direct-global) --------
// wave = one 16-row q-chunk pair (p, 127-p); no __syncthreads anywhere.
// K, Q, V^T fragments load straight from global; only P round-trips through
// a private per-wave LDS region (same-wave RAW -> lgkmcnt only).
#define LDPW 72   // padded P row stride in ushorts

__global__ __launch_bounds__(256) void attn_mfma4(
    const ushort* __restrict__ QKV, const ushort* __restrict__ Vt,
    ushort* __restrict__ AOb) {
    __shared__ ushort Ps[4 * 16 * LDPW];

    const int bh   = blockIdx.x;          // grid.x=32 -> XCD = bh%8 (L2 locality)
    const int b    = bh >> 4, h = bh & 15;
    const int t    = threadIdx.x;
    const int lane = t & 63, w = t >> 6;
    const int quad = lane >> 4, l15 = lane & 15;
    ushort* Pw = &Ps[w * 16 * LDPW];

    const size_t qbase = (size_t)b * SEQ * QKVS + h * 64;
    const ushort* Kbp = QKV + qbase + 1024;
    const ushort* Vbp = Vt + (size_t)bh * 64 * SEQ;

    const int p = blockIdx.y * 4 + w;     // pair 0..63

#pragma unroll
    for (int ph = 0; ph < 2; ++ph) {
        const int c = ph ? (127 - p) : p; // q-chunk 0..127 (16 rows)

        // Q B-fragments straight from global (already scaled by SCLQ in GEMM)
        const ushort* qp = QKV + qbase + (size_t)(c * 16 + l15) * QKVS + quad * 8;
        const short8 bq0 = *(const short8*)qp;
        const short8 bq1 = *(const short8*)(qp + 32);

        f32x4 acc_o[4];
#pragma unroll
        for (int nd = 0; nd < 4; ++nd) acc_o[nd] = (f32x4){0.f, 0.f, 0.f, 0.f};
        float m_l = -3.0e38f, l_l = 0.f;  // softmax state for q = c*16 + l15
        const int qrow = c * 16 + l15;
        const int ktl  = c >> 2;          // last (diagonal) key tile

        for (int kt = 0; kt <= ktl; ++kt) {
            const bool diag = (kt == ktl);

            // K A-frags: 8 x b128 direct from global (one 64B line per row)
            short8 ak[4][2];
#pragma unroll
            for (int kg = 0; kg < 4; ++kg) {
                const ushort* kp = Kbp + (size_t)(kt * 64 + kg * 16 + l15) * QKVS + quad * 8;
                ak[kg][0] = *(const short8*)kp;
                ak[kg][1] = *(const short8*)(kp + 32);
            }
            // V^T B-frags: 8 x b128 direct from global
            short8 bv[4][2];
#pragma unroll
            for (int nd = 0; nd < 4; ++nd) {
                const ushort* vp = Vbp + (size_t)(nd * 16 + l15) * SEQ + kt * 64 + quad * 8;
                bv[nd][0] = *(const short8*)vp;
                bv[nd][1] = *(const short8*)(vp + 32);
            }

            // ---- S^T = K Q'^T : lane holds (key=kg*16+quad*4+r, q=l15) ----
            float sv[4][4];
            float mloc = m_l;
#pragma unroll
            for (int kg = 0; kg < 4; ++kg) {
                f32x4 a = (f32x4){0.f, 0.f, 0.f, 0.f};
                a = __builtin_amdgcn_mfma_f32_16x16x32_bf16(ak[kg][0], bq0, a, 0, 0, 0);
                a = __builtin_amdgcn_mfma_f32_16x16x32_bf16(ak[kg][1], bq1, a, 0, 0, 0);
                if (diag) {
                    const int keyb = kt * 64 + kg * 16 + quad * 4;
#pragma unroll
                    for (int r = 0; r < 4; ++r) {
                        float v = (keyb + r > qrow) ? -3.0e38f : a[r];
                        sv[kg][r] = v;
                        mloc = fmaxf(mloc, v);
                    }
                } else {
#pragma unroll
                    for (int r = 0; r < 4; ++r) {
                        sv[kg][r] = a[r];
                        mloc = fmaxf(mloc, a[r]);
                    }
                }
            }
            mloc = fmaxf(mloc, __shfl_xor(mloc, 16, 64));
            mloc = fmaxf(mloc, __shfl_xor(mloc, 32, 64));
            const float alpha = exp2_fast(m_l - mloc);
            m_l = mloc;
            float rs = 0.f;
#pragma unroll
            for (int kg = 0; kg < 4; ++kg)
#pragma unroll
                for (int r = 0; r < 4; ++r) {
                    float pv = exp2_fast(sv[kg][r] - mloc);
                    sv[kg][r] = pv;
                    rs += pv;
                }
            rs += __shfl_xor(rs, 16, 64);
            rs += __shfl_xor(rs, 32, 64);
            l_l = l_l * alpha + rs;

            // rescale O accumulator (acc row q = quad*4+r)
            float av[4];
#pragma unroll
            for (int r = 0; r < 4; ++r) av[r] = __shfl(alpha, quad * 4 + r, 64);
#pragma unroll
            for (int nd = 0; nd < 4; ++nd)
#pragma unroll
                for (int r = 0; r < 4; ++r) acc_o[nd][r] *= av[r];

            // ---- P: C-layout -> A-layout via private per-wave LDS ----
#pragma unroll
            for (int kg = 0; kg < 4; ++kg) {
                uint2 u;
                u.x = pack_bf16x2(sv[kg][0], sv[kg][1]);
                u.y = pack_bf16x2(sv[kg][2], sv[kg][3]);
                *(uint2*)&Pw[l15 * LDPW + kg * 16 + quad * 4] = u;
            }
            const short8 pa0 = *(const short8*)&Pw[l15 * LDPW + quad * 8];
            const short8 pa1 = *(const short8*)&Pw[l15 * LDPW + 32 + quad * 8];
#pragma unroll
            for (int nd = 0; nd < 4; ++nd) {
                acc_o[nd] = __builtin_amdgcn_mfma_f32_16x16x32_bf16(pa0, bv[nd][0], acc_o[nd], 0, 0, 0);
                acc_o[nd] = __builtin_amdgcn_mfma_f32_16x16x32_bf16(pa1, bv[nd][1], acc_o[nd], 0, 0, 0);
            }
        }

        // ---- epilogue: normalize, store bf16 ----
        float linv[4];
#pragma unroll
        for (int r = 0; r < 4; ++r) linv[r] = 1.0f / __shfl(l_l, quad * 4 + r, 64);
#pragma unroll
        for (int nd = 0; nd < 4; ++nd)
#pragma unroll
            for (int r = 0; r < 4; ++r) {
                const int row = c * 16 + quad * 4 + r;
                AOb[(size_t)(b * SEQ + row) * EMB + h * 64 + nd * 16 + l15] =
                    bf16_1(acc_o[nd][r] * linv[r]);
            }
    }
}

// ---------------- fp32 fallback GEMM ----------------
#define BM 64
#define BN 64
#define BK 16

__global__ __launch_bounds__(256) void gemm_f32(
    const float* __restrict__ A, const float* __restrict__ B,
    float* __restrict__ C, const float* __restrict__ pos, int addpos,
    int M, int N, int K) {
    __shared__ float As[BK][BM];
    __shared__ float Bs[BK][BN];
    const int tid = threadIdx.x;
    const int bm  = blockIdx.x * BM;
    const int bn  = blockIdx.y * BN;
    const int tx  = tid & 15;
    const int ty  = tid >> 4;
    const int arow = tid >> 2;
    const int acol = (tid & 3) << 2;
    const int brow = tid >> 4;
    const int bcol = (tid & 15) << 2;
    float acc[4][4] = {{0.f}};
    const float* Aptr = A + (size_t)(bm + arow) * K + acol;
    const float* Bptr = B + (size_t)brow * N + bn + bcol;
    for (int k0 = 0; k0 < K; k0 += BK) {
        float4 av = *(const float4*)(Aptr + k0);
        float4 bv = *(const float4*)(Bptr + (size_t)k0 * N);
        __syncthreads();
        As[acol + 0][arow] = av.x;
        As[acol + 1][arow] = av.y;
        As[acol + 2][arow] = av.z;
        As[acol + 3][arow] = av.w;
        *(float4*)&Bs[brow][bcol] = bv;
        __syncthreads();
#pragma unroll
        for (int kk = 0; kk < BK; ++kk) {
            float4 a = *(const float4*)&As[kk][ty << 2];
            float4 b = *(const float4*)&Bs[kk][tx << 2];
            float aa[4] = {a.x, a.y, a.z, a.w};
            float bb[4] = {b.x, b.y, b.z, b.w};
#pragma unroll
            for (int i = 0; i < 4; ++i)
#pragma unroll
                for (int j = 0; j < 4; ++j)
                    acc[i][j] += aa[i] * bb[j];
        }
    }
#pragma unroll
    for (int i = 0; i < 4; ++i) {
        int m = bm + (ty << 2) + i;
        int n = bn + (tx << 2);
        float4 v = make_float4(acc[i][0], acc[i][1], acc[i][2], acc[i][3]);
        if (addpos) {
            int s = m & (SEQ - 1);
            int d = n & (DHEAD - 1);
            float4 p = *(const float4*)&pos[s * DHEAD + d];
            v.x += p.x; v.y += p.y; v.z += p.z; v.w += p.w;
        }
        *(float4*)&C[(size_t)m * N + n] = v;
    }
}

// ---------------- fp32 fallback attention ----------------
#define QT 128
#define KT 32
__global__ __launch_bounds__(QT) void attn_fwd(
    const float* __restrict__ Q, const float* __restrict__ Kg,
    const float* __restrict__ V, float* __restrict__ O) {
    __shared__ float Ks[KT][DHEAD];
    __shared__ float Vs[KT][DHEAD];
    const int t    = threadIdx.x;
    const int q0   = blockIdx.x * QT;
    const int bh   = blockIdx.y;
    const int b    = bh >> 4;
    const int h    = bh & 15;
    const int qrow = q0 + t;
    const size_t base = (size_t)b * SEQ * EMB + (size_t)h * DHEAD;
    float4 q4[16], o4[16];
#pragma unroll
    for (int i = 0; i < 16; ++i) {
        q4[i] = *(const float4*)&Q[base + (size_t)qrow * EMB + i * 4];
        o4[i] = make_float4(0.f, 0.f, 0.f, 0.f);
    }
    float m_i = -3.0e38f, l_i = 0.0f;
    const float scale = 0.03125f;
    const int kend = q0 + QT;
    for (int k0 = 0; k0 < kend; k0 += KT) {
        __syncthreads();
#pragma unroll
        for (int i = 0; i < 4; ++i) {
            int idx = t + i * QT;
            int r = idx >> 4;
            int c = (idx & 15) << 2;
            *(float4*)&Ks[r][c] = *(const float4*)&Kg[base + (size_t)(k0 + r) * EMB + c];
            *(float4*)&Vs[r][c] = *(const float4*)&V [base + (size_t)(k0 + r) * EMB + c];
        }
        __syncthreads();
        float sv[KT];
        float mt = m_i;
#pragma unroll
        for (int j = 0; j < KT; ++j) {
            const float4* kr = (const float4*)Ks[j];
            float dot = 0.f;
#pragma unroll
            for (int dd = 0; dd < 16; ++dd) {
                float4 kv = kr[dd];
                dot += q4[dd].x * kv.x + q4[dd].y * kv.y +
                       q4[dd].z * kv.z + q4[dd].w * kv.w;
            }
            sv[j] = (k0 + j <= qrow) ? dot * scale : -3.0e38f;
            mt = fmaxf(mt, sv[j]);
        }
        float corr = __expf(m_i - mt);
        l_i *= corr;
#pragma unroll
        for (int i = 0; i < 16; ++i) {
            o4[i].x *= corr; o4[i].y *= corr; o4[i].z *= corr; o4[i].w *= corr;
        }
#pragma unroll
        for (int j = 0; j < KT; ++j) {
            float pp = __expf(sv[j] - mt);
            l_i += pp;
            const float4* vr = (const float4*)Vs[j];
#pragma unroll
            for (int dd = 0; dd < 16; ++dd) {
                float4 vv = vr[dd];
                o4[dd].x += pp * vv.x; o4[dd].y += pp * vv.y;
                o4[dd].z += pp * vv.z; o4[dd].w += pp * vv.w;
            }
        }
        m_i = mt;
    }
    float inv = 1.0f / l_i;
#pragma unroll
    for (int i = 0; i < 16; ++i) {
        float4 v = o4[i];
        v.x *= inv; v.y *= inv; v.z *= inv; v.w *= inv;
        *(float4*)&O[base + (size_t)qrow * EMB + i * 4] = v;
    }
}

// ---------------- launch ----------------
extern "C" void kernel_launch(void* const* d_in, const int* in_sizes, int n_in,
                              void* d_out, int out_size, void* d_ws, size_t ws_size,
                              hipStream_t stream) {
    const float* x  = (const float*)d_in[0];
    const float* Wq = (const float*)d_in[1];
    const float* Wk = (const float*)d_in[2];
    const float* Wv = (const float*)d_in[3];
    const float* Wo = (const float*)d_in[4];
    float* out = (float*)d_out;

    char* ws = (char*)d_ws;
    size_t off = 0;
    float*  pos   = (float*)(ws + off);  off += (size_t)SEQ * DHEAD * 4;
    ushort* xb    = (ushort*)(ws + off); off += (size_t)MROWS * EMB * 2;
    ushort* Wqkvt = (ushort*)(ws + off); off += (size_t)QKVS * EMB * 2;
    ushort* Wot   = (ushort*)(ws + off); off += (size_t)EMB * EMB * 2;
    ushort* QKV   = (ushort*)(ws + off); off += (size_t)MROWS * QKVS * 2;
    ushort* Vtp   = (ushort*)(ws + off); off += (size_t)MROWS * EMB * 2;
    ushort* AOb   = (ushort*)(ws + off); off += (size_t)MROWS * EMB * 2;
    const bool use_bf16 = off <= ws_size;

    const int M = MROWS, K = EMB;

    pos_init<<<SEQ, DHEAD, 0, stream>>>(pos);

    if (use_bf16) {
        const int n2 = MROWS * EMB / 2;
        cvt_bf16<<<n2 / 256, 256, 0, stream>>>(x, xb, n2);
        wt_bf16_all<<<dim3(EMB / 32, EMB / 32, 4), 256, 0, stream>>>(
            Wq, Wk, Wv, Wo, Wqkvt, Wot);

        // fused QKV projection: [4096,1024] @ [1024,3072] -> bf16, +pos, Q*scl
        gemm_mfma2<<<dim3(M / TM, QKVS / TN), 256, 0, stream>>>(
            xb, Wqkvt, QKV, pos, 1, 1, QKVS, K);

        vt_tr<<<dim3(SEQ / 64, BATCH * NHEAD), 256, 0, stream>>>(QKV, Vtp);

        attn_mfma4<<<dim3(BATCH * NHEAD, 16), 256, 0, stream>>>(QKV, Vtp, AOb);

        gemm_mfma2<<<dim3(M / TM, EMB / TN), 256, 0, stream>>>(
            AOb, Wot, out, pos, 0, 0, EMB, K);
    } else {
        // fp32 fallback
        size_t f = 0;
        float* posf = (float*)(ws + f); f += (size_t)SEQ * DHEAD * 4;
        float* Qb = (float*)(ws + f); f += (size_t)MROWS * EMB * 4;
        float* Kb = (float*)(ws + f); f += (size_t)MROWS * EMB * 4;
        float* Vb = (float*)(ws + f); f += (size_t)MROWS * EMB * 4;
        float* AO = (float*)(ws + f);
        dim3 g(M / BM, EMB / BN);
        gemm_f32<<<g, 256, 0, stream>>>(x, Wq, Qb, posf, 1, M, EMB, K);
        gemm_f32<<<g, 256, 0, stream>>>(x, Wk, Kb, posf, 1, M, EMB, K);
        gemm_f32<<<g, 256, 0, stream>>>(x, Wv, Vb, posf, 0, M, EMB, K);
        attn_fwd<<<dim3(SEQ / QT, BATCH * NHEAD), QT, 0, stream>>>(Qb, Kb, Vb, AO);
        gemm_f32<<<g, 256, 0, stream>>>(AO, Wo, out, posf, 0, M, EMB, K);
    }
}

// Round 9
// 252.118 us; speedup vs baseline: 1.1389x; 1.1389x over previous
//
#include <hip/hip_runtime.h>
#include <math.h>

#define BATCH 2
#define SEQ   2048
#define EMB   1024
#define NHEAD 16
#define DHEAD 64
#define MROWS (BATCH*SEQ)
#define QKVS  3072          // fused QKV row stride

typedef unsigned int  uint;
typedef unsigned short ushort;
typedef __attribute__((ext_vector_type(8))) short short8;
typedef __attribute__((ext_vector_type(4))) float f32x4;

// fast 2^x (bare v_exp_f32; avoids glibc __exp2f macro collision)
__device__ __forceinline__ float exp2_fast(float x) {
    return __builtin_amdgcn_exp2f(x);
}

// ---------------- positional encoding table ----------------
__global__ void pos_init(float* __restrict__ pos) {
    int s = blockIdx.x;
    int d = threadIdx.x;              // 0..63
    int i = d >> 1;
    float expo  = (float)(2 * i) / (float)DHEAD;
    float scale = 1.0f / (powf(10000.0f, expo) + 1.1920928955078125e-07f);
    float ang   = (float)s * scale;
    pos[s * DHEAD + d] = (d & 1) ? cosf(ang) : sinf(ang);
}

// ---------------- bf16 helpers ----------------
__device__ __forceinline__ uint pack_bf16x2(float a, float b) {
    union { float f; uint u; } x, y;
    x.f = a; y.f = b;
    uint ua = x.u + 0x7fffu + ((x.u >> 16) & 1u);   // RNE
    uint ub = y.u + 0x7fffu + ((y.u >> 16) & 1u);
    return (ua >> 16) | (ub & 0xffff0000u);
}
__device__ __forceinline__ ushort bf16_1(float a) {
    union { float f; uint u; } x; x.f = a;
    return (ushort)((x.u + 0x7fffu + ((x.u >> 16) & 1u)) >> 16);
}

// async global->LDS, 16B per lane (lds dest = wave-uniform base + lane*16)
__device__ __forceinline__ void gll16(const ushort* g, ushort* l) {
    __builtin_amdgcn_global_load_lds(
        (const __attribute__((address_space(1))) uint*)g,
        (__attribute__((address_space(3))) uint*)l, 16, 0, 0);
}

// ---------------- fp32 -> bf16 (rowmajor) ----------------
__global__ __launch_bounds__(256) void cvt_bf16(
    const float* __restrict__ in, ushort* __restrict__ out, int n2) {
    int gid = blockIdx.x * 256 + threadIdx.x;
    if (gid < n2) {
        float2 v = ((const float2*)in)[gid];
        ((uint*)out)[gid] = pack_bf16x2(v.x, v.y);
    }
}

// ------- all 4 weights: W[K][N] fp32 -> Wt[N][K] bf16 (transpose) ----------
__global__ __launch_bounds__(256) void wt_bf16_all(
    const float* __restrict__ Wq, const float* __restrict__ Wk,
    const float* __restrict__ Wv, const float* __restrict__ Wo,
    ushort* __restrict__ Wqkvt, ushort* __restrict__ Wot) {
    __shared__ float tile[32][33];
    const int which = blockIdx.z;
    const float* W = (which == 0) ? Wq : (which == 1) ? Wk : (which == 2) ? Wv : Wo;
    ushort* Wt = (which < 3) ? (Wqkvt + (size_t)which * 1024 * EMB) : Wot;
    const int c0 = blockIdx.x * 32;   // n-tile
    const int r0 = blockIdx.y * 32;   // k-tile
    const int tx = threadIdx.x & 31;
    const int ty = threadIdx.x >> 5;  // 0..7
#pragma unroll
    for (int i = 0; i < 4; ++i)
        tile[ty + i * 8][tx] = W[(size_t)(r0 + ty + i * 8) * EMB + c0 + tx];
    __syncthreads();
#pragma unroll
    for (int i = 0; i < 4; ++i)
        Wt[(size_t)(c0 + ty + i * 8) * EMB + r0 + tx] = bf16_1(tile[tx][ty + i * 8]);
}

// ---- QKV bf16 [token][3072] (V at col 2048) -> Vt bf16 [bh][64][SEQ] ------
__global__ __launch_bounds__(256) void vt_tr(
    const ushort* __restrict__ QKV, ushort* __restrict__ Vt) {
    __shared__ ushort tile[64][72];
    const int s0 = blockIdx.x * 64;
    const int bh = blockIdx.y;
    const int b  = bh >> 4, h = bh & 15;
    const int t  = threadIdx.x;
    const int r  = t >> 2;             // 0..63
    const int c  = (t & 3) * 16;       // 0,16,32,48
    const ushort* src = QKV + (size_t)(b * SEQ + s0 + r) * QKVS + 2048 + h * 64 + c;
    *(uint4*)&tile[r][c]     = *(const uint4*)src;
    *(uint4*)&tile[r][c + 8] = *(const uint4*)(src + 8);
    __syncthreads();
    uint ov[8];
#pragma unroll
    for (int i = 0; i < 8; ++i) {
        uint lo = tile[c + 2 * i][r];
        uint hi = tile[c + 2 * i + 1][r];
        ov[i] = lo | (hi << 16);
    }
    ushort* dst = Vt + ((size_t)bh * 64 + r) * SEQ + s0 + c;
    *(uint4*)dst       = *(uint4*)&ov[0];
    *(uint4*)(dst + 8) = *(uint4*)&ov[4];
}

// ------- bf16 MFMA GEMM (m97 recipe): C[M,N] = A[M,K] @ Bt[N,K]^T ----------
// posmode: cols<2048 get +pos; cols<1024 (Q) also folded *scale*log2e.
#define TM 128
#define TN 128
#define TK 32
#define SCLQ (0.03125f * 1.44269504088896f)

__global__ __launch_bounds__(256) void gemm_mfma2(
    const ushort* __restrict__ A, const ushort* __restrict__ Bt,
    void* __restrict__ Cv, const float* __restrict__ pos, int posmode,
    int out_bf16, int N, int K) {
    __shared__ ushort As[TM * TK];   // [m][k] contiguous (lane-linear for gll)
    __shared__ ushort Bs[TN * TK];   // [n][k]

    const int t    = threadIdx.x;
    const int lane = t & 63, w = t >> 6;
    const int quad = lane >> 4, l15 = lane & 15;
    const int bm = blockIdx.x * TM, bn = blockIdx.y * TN;
    const int wm = (w & 1) * 64, wn = (w >> 1) * 64;
    const int r0 = t >> 2, kp = (t & 3) * 8;   // staging row / k-part

    f32x4 acc[4][4];
#pragma unroll
    for (int mi = 0; mi < 4; ++mi)
#pragma unroll
        for (int ni = 0; ni < 4; ++ni)
            acc[mi][ni] = (f32x4){0.f, 0.f, 0.f, 0.f};

    const ushort* Ap0 = A  + (size_t)(bm + r0) * K + kp;
    const ushort* Ap1 = A  + (size_t)(bm + 64 + r0) * K + kp;
    const ushort* Bp0 = Bt + (size_t)(bn + r0) * K + kp;
    const ushort* Bp1 = Bt + (size_t)(bn + 64 + r0) * K + kp;
    ushort* Asd0 = &As[t * 8];
    ushort* Asd1 = &As[2048 + t * 8];
    ushort* Bsd0 = &Bs[t * 8];
    ushort* Bsd1 = &Bs[2048 + t * 8];

    for (int k0 = 0; k0 < K; k0 += TK) {
        __syncthreads();
        gll16(Ap0 + k0, Asd0);
        gll16(Ap1 + k0, Asd1);
        gll16(Bp0 + k0, Bsd0);
        gll16(Bp1 + k0, Bsd1);
        __syncthreads();

        short8 af[4], bfv[4];
#pragma unroll
        for (int mi = 0; mi < 4; ++mi)
            af[mi] = *(const short8*)&As[(wm + mi * 16 + l15) * TK + quad * 8];
#pragma unroll
        for (int ni = 0; ni < 4; ++ni)
            bfv[ni] = *(const short8*)&Bs[(wn + ni * 16 + l15) * TK + quad * 8];
#pragma unroll
        for (int mi = 0; mi < 4; ++mi)
#pragma unroll
            for (int ni = 0; ni < 4; ++ni)
                acc[mi][ni] = __builtin_amdgcn_mfma_f32_16x16x32_bf16(
                    af[mi], bfv[ni], acc[mi][ni], 0, 0, 0);
    }

#pragma unroll
    for (int mi = 0; mi < 4; ++mi) {
#pragma unroll
        for (int r = 0; r < 4; ++r) {
            const int row = bm + wm + mi * 16 + quad * 4 + r;
            const int s   = row & (SEQ - 1);
#pragma unroll
            for (int ni = 0; ni < 4; ++ni) {
                const int col = bn + wn + ni * 16 + l15;
                float v = acc[mi][ni][r];
                if (posmode) {
                    if (col < 2048) v += pos[s * DHEAD + (col & 63)];
                    if (col < 1024) v *= SCLQ;   // fold attn scale into Q
                }
                if (out_bf16) ((ushort*)Cv)[(size_t)row * N + col] = bf16_1(v);
                else          ((float*) Cv)[(size_t)row * N + col] = v;
            }
        }
    }
}

// ---- MFMA flash attention v5: 2 waves x 32q, swizzled gll K, direct V -----
// LDS: Ks 64x64 (XOR-swizzled, unpadded for global_load_lds), Ps per-wave.
// Swizzle: content(row, j) stored at chunk j^(row&7)  (j = 16B chunk 0..7)
// -> b128 fragment reads are conflict-free (8 accesses/bank = floor).
#define PSTR 72

__global__ __launch_bounds__(128) void attn_mfma5(
    const ushort* __restrict__ QKV, const ushort* __restrict__ Vt,
    ushort* __restrict__ AOb) {
    __shared__ ushort Ks[64 * 64];
    __shared__ ushort Ps[2 * 32 * PSTR];

    const int bh  = blockIdx.y;
    const int qt  = (blockIdx.x + blockIdx.y) & 31;   // swizzled q-tile
    const int b   = bh >> 4, hd = bh & 15;
    const int t   = threadIdx.x;
    const int lane = t & 63, w = t >> 6;              // w = 0,1
    const int quad = lane >> 4, l15 = lane & 15;
    ushort* Pw = &Ps[w * 32 * PSTR];

    const size_t qbase = (size_t)b * SEQ * QKVS + hd * 64;
    const ushort* Kbp = QKV + qbase + 1024;
    const ushort* Vbp = Vt + (size_t)bh * 64 * SEQ;

    // staging lane constants (gll16 source permutation for XOR swizzle)
    const int srow = lane >> 3;                  // 0..7
    const int jg   = (lane & 7) ^ srow;          // global chunk this lane fetches

    // Q fragments (B-operand), 2 column groups x 2 k-halves; Q pre-scaled
    short8 bq[2][2];
#pragma unroll
    for (int cg = 0; cg < 2; ++cg) {
        const ushort* qp = QKV + qbase +
            (size_t)(qt * 64 + w * 32 + cg * 16 + l15) * QKVS + quad * 8;
        bq[cg][0] = *(const short8*)qp;
        bq[cg][1] = *(const short8*)(qp + 32);
    }

    f32x4 acc[2][4];
#pragma unroll
    for (int cg = 0; cg < 2; ++cg)
#pragma unroll
        for (int nd = 0; nd < 4; ++nd) acc[cg][nd] = (f32x4){0.f, 0.f, 0.f, 0.f};
    float m_l[2] = {-3.0e38f, -3.0e38f}, l_l[2] = {0.f, 0.f};

    for (int kt = 0; kt <= qt; ++kt) {
        __syncthreads();                         // prev readers done with Ks
        // async K staging: wave w stages rows w*32 .. w*32+31 (swizzled)
#pragma unroll
        for (int i = 0; i < 4; ++i) {
            const int r = w * 32 + i * 8 + srow;
            gll16(Kbp + (size_t)(kt * 64 + r) * QKVS + jg * 8,
                  &Ks[(w * 32 + i * 8) * 64 + lane * 8]);
        }
        // V^T fragments direct from global (drained by the same barrier)
        short8 bv[4][2];
#pragma unroll
        for (int nd = 0; nd < 4; ++nd) {
            const ushort* vp = Vbp + (size_t)(nd * 16 + l15) * SEQ + kt * 64 + quad * 8;
            bv[nd][0] = *(const short8*)vp;
            bv[nd][1] = *(const short8*)(vp + 32);
        }
        __syncthreads();                         // K DMA + V loads complete

        // ---- S^T = K Q^T for both column groups (share ak reads) ----
        const bool diag = (kt == qt);
        float sv[2][4][4];
        float ml0 = m_l[0], ml1 = m_l[1];
#pragma unroll
        for (int kg = 0; kg < 4; ++kg) {
            const int rw = (kg * 16 + l15) * 64;
            const int sx = l15 & 7;
            const short8 ak0 = *(const short8*)&Ks[rw + ((quad ^ sx) * 8)];
            const short8 ak1 = *(const short8*)&Ks[rw + (((quad + 4) ^ sx) * 8)];
            f32x4 a0 = (f32x4){0.f, 0.f, 0.f, 0.f};
            a0 = __builtin_amdgcn_mfma_f32_16x16x32_bf16(ak0, bq[0][0], a0, 0, 0, 0);
            a0 = __builtin_amdgcn_mfma_f32_16x16x32_bf16(ak1, bq[0][1], a0, 0, 0, 0);
            f32x4 a1 = (f32x4){0.f, 0.f, 0.f, 0.f};
            a1 = __builtin_amdgcn_mfma_f32_16x16x32_bf16(ak0, bq[1][0], a1, 0, 0, 0);
            a1 = __builtin_amdgcn_mfma_f32_16x16x32_bf16(ak1, bq[1][1], a1, 0, 0, 0);
            if (diag) {
                const int keyb = kt * 64 + kg * 16 + quad * 4;
                const int q0g  = qt * 64 + w * 32 + l15;
#pragma unroll
                for (int r = 0; r < 4; ++r) {
                    sv[0][kg][r] = (keyb + r > q0g)      ? -3.0e38f : a0[r];
                    sv[1][kg][r] = (keyb + r > q0g + 16) ? -3.0e38f : a1[r];
                    ml0 = fmaxf(ml0, sv[0][kg][r]);
                    ml1 = fmaxf(ml1, sv[1][kg][r]);
                }
            } else {
#pragma unroll
                for (int r = 0; r < 4; ++r) {
                    sv[0][kg][r] = a0[r];
                    sv[1][kg][r] = a1[r];
                    ml0 = fmaxf(ml0, a0[r]);
                    ml1 = fmaxf(ml1, a1[r]);
                }
            }
        }

        // ---- softmax + P + PV per column group ----
        float mlv[2] = {ml0, ml1};
#pragma unroll
        for (int cg = 0; cg < 2; ++cg) {
            float mloc = mlv[cg];
            mloc = fmaxf(mloc, __shfl_xor(mloc, 16, 64));
            mloc = fmaxf(mloc, __shfl_xor(mloc, 32, 64));
            const float alpha = exp2_fast(m_l[cg] - mloc);
            m_l[cg] = mloc;
            float rs = 0.f;
#pragma unroll
            for (int kg = 0; kg < 4; ++kg)
#pragma unroll
                for (int r = 0; r < 4; ++r) {
                    float pv = exp2_fast(sv[cg][kg][r] - mloc);
                    sv[cg][kg][r] = pv;
                    rs += pv;
                }
            rs += __shfl_xor(rs, 16, 64);
            rs += __shfl_xor(rs, 32, 64);
            l_l[cg] = l_l[cg] * alpha + rs;

            float av[4];
#pragma unroll
            for (int r = 0; r < 4; ++r) av[r] = __shfl(alpha, quad * 4 + r, 64);
#pragma unroll
            for (int nd = 0; nd < 4; ++nd)
#pragma unroll
                for (int r = 0; r < 4; ++r) acc[cg][nd][r] *= av[r];

            // P write: P^T(key, q) -> Pw[q_local][key]  (wave-private)
#pragma unroll
            for (int kg = 0; kg < 4; ++kg) {
                uint2 u;
                u.x = pack_bf16x2(sv[cg][kg][0], sv[cg][kg][1]);
                u.y = pack_bf16x2(sv[cg][kg][2], sv[cg][kg][3]);
                *(uint2*)&Pw[(cg * 16 + l15) * PSTR + kg * 16 + quad * 4] = u;
            }
            const short8 pa0 = *(const short8*)&Pw[(cg * 16 + l15) * PSTR + quad * 8];
            const short8 pa1 = *(const short8*)&Pw[(cg * 16 + l15) * PSTR + 32 + quad * 8];
#pragma unroll
            for (int nd = 0; nd < 4; ++nd) {
                acc[cg][nd] = __builtin_amdgcn_mfma_f32_16x16x32_bf16(pa0, bv[nd][0], acc[cg][nd], 0, 0, 0);
                acc[cg][nd] = __builtin_amdgcn_mfma_f32_16x16x32_bf16(pa1, bv[nd][1], acc[cg][nd], 0, 0, 0);
            }
        }
    }

    // ---- epilogue ----
#pragma unroll
    for (int cg = 0; cg < 2; ++cg) {
        float linv[4];
#pragma unroll
        for (int r = 0; r < 4; ++r) linv[r] = 1.0f / __shfl(l_l[cg], quad * 4 + r, 64);
#pragma unroll
        for (int nd = 0; nd < 4; ++nd)
#pragma unroll
            for (int r = 0; r < 4; ++r) {
                const int row = qt * 64 + w * 32 + cg * 16 + quad * 4 + r;
                AOb[(size_t)(b * SEQ + row) * EMB + hd * 64 + nd * 16 + l15] =
                    bf16_1(acc[cg][nd][r] * linv[r]);
            }
    }
}

// ---------------- fp32 fallback GEMM ----------------
#define BM 64
#define BN 64
#define BK 16

__global__ __launch_bounds__(256) void gemm_f32(
    const float* __restrict__ A, const float* __restrict__ B,
    float* __restrict__ C, const float* __restrict__ pos, int addpos,
    int M, int N, int K) {
    __shared__ float As[BK][BM];
    __shared__ float Bs[BK][BN];
    const int tid = threadIdx.x;
    const int bm  = blockIdx.x * BM;
    const int bn  = blockIdx.y * BN;
    const int tx  = tid & 15;
    const int ty  = tid >> 4;
    const int arow = tid >> 2;
    const int acol = (tid & 3) << 2;
    const int brow = tid >> 4;
    const int bcol = (tid & 15) << 2;
    float acc[4][4] = {{0.f}};
    const float* Aptr = A + (size_t)(bm + arow) * K + acol;
    const float* Bptr = B + (size_t)brow * N + bn + bcol;
    for (int k0 = 0; k0 < K; k0 += BK) {
        float4 av = *(const float4*)(Aptr + k0);
        float4 bv = *(const float4*)(Bptr + (size_t)k0 * N);
        __syncthreads();
        As[acol + 0][arow] = av.x;
        As[acol + 1][arow] = av.y;
        As[acol + 2][arow] = av.z;
        As[acol + 3][arow] = av.w;
        *(float4*)&Bs[brow][bcol] = bv;
        __syncthreads();
#pragma unroll
        for (int kk = 0; kk < BK; ++kk) {
            float4 a = *(const float4*)&As[kk][ty << 2];
            float4 b = *(const float4*)&Bs[kk][tx << 2];
            float aa[4] = {a.x, a.y, a.z, a.w};
            float bb[4] = {b.x, b.y, b.z, b.w};
#pragma unroll
            for (int i = 0; i < 4; ++i)
#pragma unroll
                for (int j = 0; j < 4; ++j)
                    acc[i][j] += aa[i] * bb[j];
        }
    }
#pragma unroll
    for (int i = 0; i < 4; ++i) {
        int m = bm + (ty << 2) + i;
        int n = bn + (tx << 2);
        float4 v = make_float4(acc[i][0], acc[i][1], acc[i][2], acc[i][3]);
        if (addpos) {
            int s = m & (SEQ - 1);
            int d = n & (DHEAD - 1);
            float4 p = *(const float4*)&pos[s * DHEAD + d];
            v.x += p.x; v.y += p.y; v.z += p.z; v.w += p.w;
        }
        *(float4*)&C[(size_t)m * N + n] = v;
    }
}

// ---------------- fp32 fallback attention ----------------
#define QT 128
#define KT 32
__global__ __launch_bounds__(QT) void attn_fwd(
    const float* __restrict__ Q, const float* __restrict__ Kg,
    const float* __restrict__ V, float* __restrict__ O) {
    __shared__ float Ks[KT][DHEAD];
    __shared__ float Vs[KT][DHEAD];
    const int t    = threadIdx.x;
    const int q0   = blockIdx.x * QT;
    const int bh   = blockIdx.y;
    const int b    = bh >> 4;
    const int h    = bh & 15;
    const int qrow = q0 + t;
    const size_t base = (size_t)b * SEQ * EMB + (size_t)h * DHEAD;
    float4 q4[16], o4[16];
#pragma unroll
    for (int i = 0; i < 16; ++i) {
        q4[i] = *(const float4*)&Q[base + (size_t)qrow * EMB + i * 4];
        o4[i] = make_float4(0.f, 0.f, 0.f, 0.f);
    }
    float m_i = -3.0e38f, l_i = 0.0f;
    const float scale = 0.03125f;
    const int kend = q0 + QT;
    for (int k0 = 0; k0 < kend; k0 += KT) {
        __syncthreads();
#pragma unroll
        for (int i = 0; i < 4; ++i) {
            int idx = t + i * QT;
            int r = idx >> 4;
            int c = (idx & 15) << 2;
            *(float4*)&Ks[r][c] = *(const float4*)&Kg[base + (size_t)(k0 + r) * EMB + c];
            *(float4*)&Vs[r][c] = *(const float4*)&V [base + (size_t)(k0 + r) * EMB + c];
        }
        __syncthreads();
        float sv[KT];
        float mt = m_i;
#pragma unroll
        for (int j = 0; j < KT; ++j) {
            const float4* kr = (const float4*)Ks[j];
            float dot = 0.f;
#pragma unroll
            for (int dd = 0; dd < 16; ++dd) {
                float4 kv = kr[dd];
                dot += q4[dd].x * kv.x + q4[dd].y * kv.y +
                       q4[dd].z * kv.z + q4[dd].w * kv.w;
            }
            sv[j] = (k0 + j <= qrow) ? dot * scale : -3.0e38f;
            mt = fmaxf(mt, sv[j]);
        }
        float corr = __expf(m_i - mt);
        l_i *= corr;
#pragma unroll
        for (int i = 0; i < 16; ++i) {
            o4[i].x *= corr; o4[i].y *= corr; o4[i].z *= corr; o4[i].w *= corr;
        }
#pragma unroll
        for (int j = 0; j < KT; ++j) {
            float pp = __expf(sv[j] - mt);
            l_i += pp;
            const float4* vr = (const float4*)Vs[j];
#pragma unroll
            for (int dd = 0; dd < 16; ++dd) {
                float4 vv = vr[dd];
                o4[dd].x += pp * vv.x; o4[dd].y += pp * vv.y;
                o4[dd].z += pp * vv.z; o4[dd].w += pp * vv.w;
            }
        }
        m_i = mt;
    }
    float inv = 1.0f / l_i;
#pragma unroll
    for (int i = 0; i < 16; ++i) {
        float4 v = o4[i];
        v.x *= inv; v.y *= inv; v.z *= inv; v.w *= inv;
        *(float4*)&O[base + (size_t)qrow * EMB + i * 4] = v;
    }
}

// ---------------- launch ----------------
extern "C" void kernel_launch(void* const* d_in, const int* in_sizes, int n_in,
                              void* d_out, int out_size, void* d_ws, size_t ws_size,
                              hipStream_t stream) {
    const float* x  = (const float*)d_in[0];
    const float* Wq = (const float*)d_in[1];
    const float* Wk = (const float*)d_in[2];
    const float* Wv = (const float*)d_in[3];
    const float* Wo = (const float*)d_in[4];
    float* out = (float*)d_out;

    char* ws = (char*)d_ws;
    size_t off = 0;
    float*  pos   = (float*)(ws + off);  off += (size_t)SEQ * DHEAD * 4;
    ushort* xb    = (ushort*)(ws + off); off += (size_t)MROWS * EMB * 2;
    ushort* Wqkvt = (ushort*)(ws + off); off += (size_t)QKVS * EMB * 2;
    ushort* Wot   = (ushort*)(ws + off); off += (size_t)EMB * EMB * 2;
    ushort* QKV   = (ushort*)(ws + off); off += (size_t)MROWS * QKVS * 2;
    ushort* Vtp   = (ushort*)(ws + off); off += (size_t)MROWS * EMB * 2;
    ushort* AOb   = (ushort*)(ws + off); off += (size_t)MROWS * EMB * 2;
    const bool use_bf16 = off <= ws_size;

    const int M = MROWS, K = EMB;

    pos_init<<<SEQ, DHEAD, 0, stream>>>(pos);

    if (use_bf16) {
        const int n2 = MROWS * EMB / 2;
        cvt_bf16<<<n2 / 256, 256, 0, stream>>>(x, xb, n2);
        wt_bf16_all<<<dim3(EMB / 32, EMB / 32, 4), 256, 0, stream>>>(
            Wq, Wk, Wv, Wo, Wqkvt, Wot);

        // fused QKV projection: [4096,1024] @ [1024,3072] -> bf16, +pos, Q*scl
        gemm_mfma2<<<dim3(M / TM, QKVS / TN), 256, 0, stream>>>(
            xb, Wqkvt, QKV, pos, 1, 1, QKVS, K);

        vt_tr<<<dim3(SEQ / 64, BATCH * NHEAD), 256, 0, stream>>>(QKV, Vtp);

        attn_mfma5<<<dim3(32, BATCH * NHEAD), 128, 0, stream>>>(QKV, Vtp, AOb);

        gemm_mfma2<<<dim3(M / TM, EMB / TN), 256, 0, stream>>>(
            AOb, Wot, out, pos, 0, 0, EMB, K);
    } else {
        // fp32 fallback
        size_t f = 0;
        float* posf = (float*)(ws + f); f += (size_t)SEQ * DHEAD * 4;
        float* Qb = (float*)(ws + f); f += (size_t)MROWS * EMB * 4;
        float* Kb = (float*)(ws + f); f += (size_t)MROWS * EMB * 4;
        float* Vb = (float*)(ws + f); f += (size_t)MROWS * EMB * 4;
        float* AO = (float*)(ws + f);
        dim3 g(M / BM, EMB / BN);
        gemm_f32<<<g, 256, 0, stream>>>(x, Wq, Qb, posf, 1, M, EMB, K);
        gemm_f32<<<g, 256, 0, stream>>>(x, Wk, Kb, posf, 1, M, EMB, K);
        gemm_f32<<<g, 256, 0, stream>>>(x, Wv, Vb, posf, 0, M, EMB, K);
        attn_fwd<<<dim3(SEQ / QT, BATCH * NHEAD), QT, 0, stream>>>(Qb, Kb, Vb, AO);
        gemm_f32<<<g, 256, 0, stream>>>(AO, Wo, out, posf, 0, M, EMB, K);
    }
}